// Round 15
// baseline (85.941 us; speedup 1.0000x reference)
//
#include <hip/hip_runtime.h>
#include <math.h>

#define NGRAPH 256
#define NPG 256
#define HF 128
#define EPG 4096      // real edges per graph
#define EPG2 4352     // max CSR slots incl one self-edge per node
#define FSTR 132      // f32 row stride in tbufF (aliases hpair)
#define PSTR 136      // short row stride in hpair

typedef __attribute__((ext_vector_type(8))) short bf16x8;
typedef __attribute__((ext_vector_type(4))) float f32x4;

template<int N> struct IC { static constexpr int value = N; };
template<bool B> struct BC { static constexpr bool value = B; };

static __device__ __forceinline__ unsigned bcu(float f){ return __builtin_bit_cast(unsigned, f); }
static __device__ __forceinline__ float bcf(unsigned u){ return __builtin_bit_cast(float, u); }
static __device__ __forceinline__ unsigned rtn16(float f){
  unsigned u = bcu(f);
  return (u + 0x7FFFu + ((u >> 16) & 1u)) >> 16;
}

// ---------------- W transpose + split to bf16 hi/lo: Wt[n][k] ----------------
__global__ __launch_bounds__(256) void prep_wt(const float* __restrict__ W1,
                                               const float* __restrict__ W2,
                                               const float* __restrict__ W3,
                                               short* __restrict__ Wt) {
  int idx = blockIdx.x * 256 + threadIdx.x;
  int L = idx >> 14, r = idx & 16383;
  int k = r >> 7, n = r & 127;
  const float* W = (L == 0) ? W1 : (L == 1) ? W2 : W3;
  float w = W[k*128 + n];
  unsigned hi = rtn16(w);
  float lo = w - bcf(hi << 16);
  short* Whi = Wt + (size_t)L * 2 * 16384;
  short* Wlo = Whi + 16384;
  Whi[n*128 + k] = (short)hi;
  Wlo[n*128 + k] = (short)(bcu(lo) >> 16);
}

// sort compare-exchange step (descending key, ascending idx on ties)
#define BSTEP(OK, OI, KKc, Jc) do { \
  bool iLess = ((tid & (Jc)) == 0); \
  bool descR = ((tid & (KKc)) == 0); \
  bool myFirst = (kf > (OK)) || (kf == (OK) && ki < (OI)); \
  bool keep = (iLess == descR) ? myFirst : !myFirst; \
  if (!keep) { kf = (OK); ki = (OI); } \
} while (0)

// single-wave exclusive scan of cntA -> rloc + curA; rloc[NPG] = total
#define WAVE0_SCAN() do { \
  if (wid == 0) { \
    int b4 = lane*4; \
    int c0=cntA[b4+0], c1=cntA[b4+1], c2=cntA[b4+2], c3=cntA[b4+3]; \
    int tot = c0+c1+c2+c3; \
    int run = tot; \
    _Pragma("unroll") \
    for (int off=1; off<64; off<<=1) { \
      int u = __shfl_up(run, off); \
      run += (lane >= off) ? u : 0; \
    } \
    int st = run - tot; \
    rloc[b4+0]=(unsigned short)st; \
    rloc[b4+1]=(unsigned short)(st+c0); \
    rloc[b4+2]=(unsigned short)(st+c0+c1); \
    rloc[b4+3]=(unsigned short)(st+c0+c1+c2); \
    curA[b4+0]=st; curA[b4+1]=st+c0; curA[b4+2]=st+c0+c1; curA[b4+3]=st+c0+c1+c2; \
    if (lane == 63) rloc[NPG] = (unsigned short)run; \
  } \
} while (0)

// ---------------- whole network, one block per graph ----------------
__global__ __launch_bounds__(1024, 4)
void fused_net(
    const float* __restrict__ x,
    const int* __restrict__ srcI, const int* __restrict__ dstI,
    const short* __restrict__ WtAll,
    const float* __restrict__ b1, const float* __restrict__ Ws1, const float* __restrict__ bs1,
    const float* __restrict__ b2, const float* __restrict__ Ws2, const float* __restrict__ bs2,
    const float* __restrict__ b3, const float* __restrict__ Ws3, const float* __restrict__ bs3,
    const float* __restrict__ Wl1, const float* __restrict__ bl1,
    const float* __restrict__ Wl2, const float* __restrict__ bl2,
    const float* __restrict__ Wl3, const float* __restrict__ bl3,
    float* __restrict__ out)
{
  __shared__ __align__(16) short hpair[2][NPG*PSTR];   // 139264 B; aliased by tbufF
  __shared__ unsigned char colS[EPG2 + 8];             // compacted CSR (current ids), incl self
  __shared__ unsigned short rloc[NPG+2];
  __shared__ unsigned selM[8];                         // selection bitmask (current ids)
  __shared__ float dinv[NPG];
  __shared__ __align__(16) float bvec[HF];
  __shared__ __align__(16) float wsv[HF];
  __shared__ float score[NPG];
  __shared__ float tscale[NPG];                        // tq scratch / tanh scale
  __shared__ float skey[NPG];
  __shared__ int   sidx[NPG];
  __shared__ unsigned char rank8[NPG];                 // current id -> next id (0xFF dead)
  __shared__ unsigned char lut[NPG];                   // ORIGINAL id -> current id (0xFF dead)
  __shared__ __align__(16) float red[1024];            // readout max / MLP scratch
  __shared__ __align__(16) float red2[1024];           // readout sum
  __shared__ float zacc[2*HF];

  float* tbufF = (float*)&hpair[0][0];                 // [row][FSTR] f32, alias
  short* hp0 = &hpair[0][0];
  short* hp1 = &hpair[1][0];
  int* cntA = (int*)skey;                              // degree counts (alias: sort scratch)
  int* curA = sidx;

  int tid = threadIdx.x;
  int g = blockIdx.x;
  size_t nbase = (size_t)g * NPG;
  int lane = tid & 63, wid = tid >> 6;

  // ---- stage x into bf16 hi/lo pair ----
  const float4* X4 = (const float4*)(x + nbase*HF);
  #pragma unroll
  for (int i = 0; i < 8; ++i) {
    int f4 = tid + i*1024;
    int r = f4 >> 5, kq = f4 & 31;
    float4 val = X4[f4];
    unsigned rx = rtn16(val.x), ry = rtn16(val.y), rz = rtn16(val.z), rw = rtn16(val.w);
    uint2 ph; ph.x = rx | (ry << 16); ph.y = rz | (rw << 16);
    float lx = val.x - bcf(rx << 16), ly = val.y - bcf(ry << 16);
    float lz = val.z - bcf(rz << 16), lw = val.w - bcf(rw << 16);
    uint2 pl; pl.x = (bcu(lx) >> 16) | (bcu(ly) & 0xFFFF0000u);
    pl.y = (bcu(lz) >> 16) | (bcu(lw) & 0xFFFF0000u);
    *(uint2*)&hp0[r*PSTR + kq*4] = ph;
    *(uint2*)&hp1[r*PSTR + kq*4] = pl;
  }

  // ---- edges into registers (ORIGINAL local ids, kept all layers) ----
  int nb = g * NPG;
  int dloc[4], sloc[4];
  #pragma unroll
  for (int it = 0; it < 4; ++it) {
    int e = g*EPG + tid + it*1024;
    dloc[it] = dstI[e] - nb;
    sloc[it] = srcI[e] - nb;
  }

  // ---- initial CSR build (all alive, +1 self slot per node) + lut identity ----
  if (tid < NPG) { cntA[tid] = 1; lut[tid] = (unsigned char)tid; }
  __syncthreads();
  #pragma unroll
  for (int it = 0; it < 4; ++it) atomicAdd(&cntA[dloc[it]], 1);
  __syncthreads();
  WAVE0_SCAN();
  __syncthreads();
  #pragma unroll
  for (int it = 0; it < 4; ++it) {
    int slot = atomicAdd(&curA[dloc[it]], 1);
    colS[slot] = (unsigned char)sloc[it];
  }
  if (tid < NPG) colS[rloc[tid+1] - 1] = (unsigned char)tid;
  // NOTE: cntA (=skey) still holds degrees; layer 1 derives dinv from it.

  // ================= layer template =================
  auto run_layer = [&](auto nrc, auto kc, auto firstc, auto packc, auto buildc,
                       const short* Whi, const short* Wlo,
                       const float* bias, const float* Wsc, const float* bscp) {
    constexpr int NR = decltype(nrc)::value;      // rows in (compacted)
    constexpr int K  = decltype(kc)::value;       // rows out
    constexpr bool FIRST = decltype(firstc)::value;
    constexpr bool PACK  = decltype(packc)::value;
    constexpr bool BUILD = decltype(buildc)::value;  // build own CSR (counts from prev layer)
    constexpr int TPN = 1024 / NR;                // threads per node: 4,8,16
    constexpr int NI  = 32 / TPN;                 // float4s per thread: 8,4,2
    constexpr int SH  = (TPN == 4) ? 2 : ((TPN == 8) ? 3 : 4);
    constexpr int RT  = NR / 64;                  // transform row tiles per wave: 4,2,1
    int v = tid >> SH, q = tid & (TPN - 1);
    int cb0 = 4 * q;

    __syncthreads();   // B0: pack + counts (cntA) visible

    if (tid < HF) { bvec[tid] = bias[tid]; wsv[tid] = Wsc[tid]; }
    float bscv = bscp[0];
    if (tid < NR) dinv[tid] = 1.0f / sqrtf((float)cntA[tid]);
    if constexpr (BUILD) WAVE0_SCAN();   // wave0: counts -> rloc/curA (overlaps MFMA)

    // ---- transform: G = dinv * (h @ W), 4rg x 4cg waves, all active ----
    {
      int rg = wid & 3, cg = wid >> 2;
      int lr = lane & 15, lk8 = (lane >> 4) * 8;
      f32x4 tacc[RT][2] = {};
      #pragma unroll
      for (int kc2 = 0; kc2 < 4; ++kc2) {
        int k0 = kc2*32 + lk8;
        bf16x8 ah[RT], al[RT];
        #pragma unroll
        for (int rt = 0; rt < RT; ++rt) {
          int row = rg*(NR/4) + rt*16 + lr;
          ah[rt] = *(const bf16x8*)&hp0[row*PSTR + k0];
          al[rt] = *(const bf16x8*)&hp1[row*PSTR + k0];
        }
        #pragma unroll
        for (int ct = 0; ct < 2; ++ct) {
          int n = cg*32 + ct*16 + lr;
          bf16x8 bh = *(const bf16x8*)&Whi[n*HF + k0];
          bf16x8 bl = *(const bf16x8*)&Wlo[n*HF + k0];
          #pragma unroll
          for (int rt = 0; rt < RT; ++rt) {
            tacc[rt][ct] = __builtin_amdgcn_mfma_f32_16x16x32_bf16(ah[rt], bh, tacc[rt][ct], 0, 0, 0);
            tacc[rt][ct] = __builtin_amdgcn_mfma_f32_16x16x32_bf16(al[rt], bh, tacc[rt][ct], 0, 0, 0);
            tacc[rt][ct] = __builtin_amdgcn_mfma_f32_16x16x32_bf16(ah[rt], bl, tacc[rt][ct], 0, 0, 0);
          }
        }
      }
      __syncthreads();   // B1: pair reads done; dinv[]/rloc/curA visible
      #pragma unroll
      for (int rt = 0; rt < RT; ++rt) {
        int row0 = rg*(NR/4) + rt*16 + (lane >> 4)*4;
        float d0 = dinv[row0+0], d1 = dinv[row0+1], d2 = dinv[row0+2], d3 = dinv[row0+3];
        #pragma unroll
        for (int ct = 0; ct < 2; ++ct) {
          int c = cg*32 + ct*16 + (lane & 15);
          tbufF[(row0+0)*FSTR + c] = tacc[rt][ct][0] * d0;
          tbufF[(row0+1)*FSTR + c] = tacc[rt][ct][1] * d1;
          tbufF[(row0+2)*FSTR + c] = tacc[rt][ct][2] * d2;
          tbufF[(row0+3)*FSTR + c] = tacc[rt][ct][3] * d3;
        }
      }
    }
    if constexpr (BUILD) {
      // scatter kept edges into fresh CSR (overlaps epilogue; colS old is dead)
      #pragma unroll
      for (int it = 0; it < 4; ++it) {
        int d2 = lut[dloc[it]], s2 = lut[sloc[it]];
        if (d2 < NR && s2 < NR) {
          int slot = atomicAdd(&curA[d2], 1);
          colS[slot] = (unsigned char)s2;
        }
      }
      if (tid < NR) colS[rloc[tid+1] - 1] = (unsigned char)tid;  // self in last slot
    }
    __syncthreads();   // B2: G + CSR ready

    // ---- aggregation: TPN threads/node, 4-deep colS prefetch; tq via shfl ----
    float4 hv[NI];
    {
      float4 acc[NI];
      #pragma unroll
      for (int j = 0; j < NI; ++j) { acc[j].x = acc[j].y = acc[j].z = acc[j].w = 0.f; }
      int e0 = rloc[v], e1 = rloc[v+1];
      int sA = colS[e0], sB = colS[e0+1], sC = colS[e0+2], sD = colS[e0+3];
      int e = e0;
      for (; e + 1 < e1; e += 2) {
        int s0 = sA, s1 = sB;
        sA = sC; sB = sD; sC = colS[e+4]; sD = colS[e+5];
        const float* g0 = &tbufF[s0*FSTR + cb0];
        const float* g1 = &tbufF[s1*FSTR + cb0];
        #pragma unroll
        for (int j = 0; j < NI; ++j) {
          float4 t0 = *(const float4*)&g0[j*4*TPN];
          float4 t1 = *(const float4*)&g1[j*4*TPN];
          acc[j].x += t0.x + t1.x; acc[j].y += t0.y + t1.y;
          acc[j].z += t0.z + t1.z; acc[j].w += t0.w + t1.w;
        }
      }
      if (e < e1) {
        const float* g0 = &tbufF[sA*FSTR + cb0];
        #pragma unroll
        for (int j = 0; j < NI; ++j) {
          float4 t0 = *(const float4*)&g0[j*4*TPN];
          acc[j].x += t0.x; acc[j].y += t0.y; acc[j].z += t0.z; acc[j].w += t0.w;
        }
      }
      float dv = dinv[v];
      float p = 0.f;
      #pragma unroll
      for (int j = 0; j < NI; ++j) {
        int ci = cb0 + j*4*TPN;
        float4 bv = *(const float4*)&bvec[ci];
        float4 wv = *(const float4*)&wsv[ci];
        float4 a;
        a.x = fmaxf(fmaf(dv, acc[j].x, bv.x), 0.f);
        a.y = fmaxf(fmaf(dv, acc[j].y, bv.y), 0.f);
        a.z = fmaxf(fmaf(dv, acc[j].z, bv.z), 0.f);
        a.w = fmaxf(fmaf(dv, acc[j].w, bv.w), 0.f);
        hv[j] = a;
        p += a.x*wv.x + a.y*wv.y + a.z*wv.z + a.w*wv.w;
      }
      // butterfly across the TPN lanes of this node (adjacent lanes)
      #pragma unroll
      for (int o = 1; o < TPN; o <<= 1) p += __shfl_xor(p, o);
      if (q == 0) {
        float t = p * dv;          // tq = (h.Ws)*dinv
        tscale[v] = t;
        score[v] = t;              // self-edge seed
      }
    }
    __syncthreads();   // B3: tq + score(self) ready, G reads done

    // ---- edge-parallel score aggregation (raw edges via lut, multiplicity kept) ----
    #pragma unroll
    for (int it = 0; it < 4; ++it) {
      int d2 = lut[dloc[it]], s2 = lut[sloc[it]];
      if (d2 < NR && s2 < NR) atomicAdd(&score[d2], tscale[s2]);
    }
    __syncthreads();   // B4: atomics done
    if (tid < NR) score[tid] = dinv[tid] * score[tid] + bscv;
    __syncthreads();   // B5: scores ready

    // ---- top-K bitonic sort over NR; idle waves: selM clear + tanh ----
    float kf = -INFINITY; int ki = tid;
    if (tid < NR) {
      kf = score[tid];
      for (int kk = 2; kk <= 64; kk <<= 1)
        for (int j = kk >> 1; j > 0; j >>= 1) {
          float ok = __shfl_xor(kf, j);
          int   oi = __shfl_xor(ki, j);
          BSTEP(ok, oi, kk, j);
        }
    } else {
      if (tid < NR + 8) selM[tid - NR] = 0u;
      int vt = tid - NR;
      if (vt < NR) tscale[vt] = tanhf(score[vt]);   // unconditional tanh (writes rank-gated)
    }

    if constexpr (NR == 256) {
      if (tid < NR) { skey[tid] = kf; sidx[tid] = ki; }
      __syncthreads();
      if (tid < NR) {
        int l = tid ^ 64; float ok = skey[l]; int oi = sidx[l];
        BSTEP(ok, oi, 128, 64);
        for (int j = 32; j > 0; j >>= 1) {
          float sk = __shfl_xor(kf, j); int si = __shfl_xor(ki, j);
          BSTEP(sk, si, 128, j);
        }
      }
      __syncthreads();
      if (tid < NR) { skey[tid] = kf; sidx[tid] = ki; }
      __syncthreads();
      if (tid < NR) {
        int l = tid ^ 128; float ok = skey[l]; int oi = sidx[l];
        BSTEP(ok, oi, 256, 128);
      }
      __syncthreads();
      if (tid < NR) { skey[tid] = kf; sidx[tid] = ki; }
      __syncthreads();
      if (tid < NR) {
        int l = tid ^ 64; float ok = skey[l]; int oi = sidx[l];
        BSTEP(ok, oi, 256, 64);
        for (int j = 32; j > 0; j >>= 1) {
          float sk = __shfl_xor(kf, j); int si = __shfl_xor(ki, j);
          BSTEP(sk, si, 256, j);
        }
      }
    } else if constexpr (NR == 128) {
      if (tid < NR) { skey[tid] = kf; sidx[tid] = ki; }
      __syncthreads();
      if (tid < NR) {
        int l = tid ^ 64; float ok = skey[l]; int oi = sidx[l];
        BSTEP(ok, oi, 128, 64);
        for (int j = 32; j > 0; j >>= 1) {
          float sk = __shfl_xor(kf, j); int si = __shfl_xor(ki, j);
          BSTEP(sk, si, 128, j);
        }
      }
    }
    if constexpr (NR == 64) __syncthreads();       // separate clear from publish
    if constexpr (NR != 64 && NR != 256) __syncthreads();
    if (tid < K) atomicOr(&selM[ki >> 5], 1u << (ki & 31));
    __syncthreads();   // B6: selection published (skey/cntA now free)

    // ---- rank (order-preserving compaction) + next-layer count init ----
    if (tid < NR) {
      unsigned wsel = selM[tid >> 5];
      bool sel = (wsel >> (tid & 31)) & 1;
      int r = __popc(wsel & ((1u << (tid & 31)) - 1u));
      for (int w = 0; w < (tid >> 5); ++w) r += __popc(selM[w]);
      rank8[tid] = sel ? (unsigned char)r : (unsigned char)0xFF;
    }
    if constexpr (PACK) {
      if (tid < NPG) cntA[tid] = (tid < K) ? 1 : 0;   // self-loop seed for next layer
    }
    __syncthreads();   // B7: rank8 ready
    if (tid < NPG) {
      int lv = lut[tid];
      lut[tid] = (lv < NR) ? rank8[lv] : (unsigned char)0xFF;
    }

    // ---- scale + write f32 h' at NEW (compacted) rows ----
    int rk = rank8[v];
    {
      float ts = tscale[v];
      if (rk != 0xFF) {
        #pragma unroll
        for (int j = 0; j < NI; ++j) {
          hv[j].x *= ts; hv[j].y *= ts; hv[j].z *= ts; hv[j].w *= ts;
          *(float4*)&tbufF[rk*FSTR + cb0 + j*4*TPN] = hv[j];
        }
      }
    }
    __syncthreads();   // B8: h' f32 ready; lut final

    // ---- readout partials + next-layer degree counts ----
    {
      constexpr int RPG = K / 8;
      int f = tid & 127, vg = tid >> 7;
      float mx = -INFINITY, sm = 0.f;
      #pragma unroll
      for (int vr = 0; vr < RPG; ++vr) {
        float val = tbufF[(vg*RPG + vr)*FSTR + f];
        mx = fmaxf(mx, val); sm += val;
      }
      red[vg*HF + f] = mx;
      red2[vg*HF + f] = sm;
    }
    if constexpr (PACK) {
      #pragma unroll
      for (int it = 0; it < 4; ++it) {
        int d2 = lut[dloc[it]], s2 = lut[sloc[it]];
        if (d2 < K && s2 < K) atomicAdd(&cntA[d2], 1);
      }
    }
    __syncthreads();   // B9: tbufF reads done; red/red2 ready; counts done
    if (tid < HF) {
      float zm = red[tid];
      float zs = red2[tid];
      #pragma unroll
      for (int q2 = 1; q2 < 8; ++q2) {
        zm = fmaxf(zm, red[q2*HF + tid]);
        zs += red2[q2*HF + tid];
      }
      float mn = zs / (float)K;
      if (FIRST) { zacc[tid] = zm; zacc[HF + tid] = mn; }
      else       { zacc[tid] += zm; zacc[HF + tid] += mn; }
    }

    if constexpr (PACK) {
      // ---- pack scaled h' into bf16 pair at NEW rows (tbufF reads done) ----
      if (rk != 0xFF) {
        #pragma unroll
        for (int j = 0; j < NI; ++j) {
          int ci = cb0 + j*4*TPN;
          float4 val = hv[j];
          unsigned rx = rtn16(val.x), ry = rtn16(val.y), rz = rtn16(val.z), rw = rtn16(val.w);
          uint2 ph; ph.x = rx | (ry << 16); ph.y = rz | (rw << 16);
          float lx = val.x - bcf(rx << 16), ly = val.y - bcf(ry << 16);
          float lz = val.z - bcf(rz << 16), lw = val.w - bcf(rw << 16);
          uint2 pl; pl.x = (bcu(lx) >> 16) | (bcu(ly) & 0xFFFF0000u);
          pl.y = (bcu(lz) >> 16) | (bcu(lw) & 0xFFFF0000u);
          *(uint2*)&hp0[rk*PSTR + ci] = ph;
          *(uint2*)&hp1[rk*PSTR + ci] = pl;
        }
      }
    }
  };

  run_layer(IC<256>{}, IC<128>{}, BC<true>{},  BC<true>{},  BC<false>{},
            WtAll,         WtAll + 16384, b1, Ws1, bs1);
  run_layer(IC<128>{}, IC<64>{},  BC<false>{}, BC<true>{},  BC<true>{},
            WtAll + 32768, WtAll + 49152, b2, Ws2, bs2);
  run_layer(IC<64>{},  IC<32>{},  BC<false>{}, BC<false>{}, BC<true>{},
            WtAll + 65536, WtAll + 81920, b3, Ws3, bs3);

  __syncthreads();

  // ---- MLP head + log_softmax ----
  {
    int o = tid & 127, kg = tid >> 7;
    float p = 0.f;
    int k0 = kg*32;
    for (int k = k0; k < k0+32; ++k) p += zacc[k]*Wl1[k*HF + o];
    red[kg*HF + o] = p;
    __syncthreads();
    if (tid < HF) {
      float a = bl1[tid];
      #pragma unroll
      for (int q2 = 0; q2 < 8; ++q2) a += red[q2*HF + tid];
      score[tid] = fmaxf(a, 0.f);       // h1
    }
    __syncthreads();
    if (tid < 512) {
      int o2 = tid & 63, kg2 = tid >> 6;
      float p2 = 0.f;
      int k0b = kg2*16;
      for (int k = k0b; k < k0b+16; ++k) p2 += score[k]*Wl2[k*64 + o2];
      red[kg2*64 + o2] = p2;
    }
    __syncthreads();
    if (tid < 64) {
      float a = bl2[tid];
      #pragma unroll
      for (int q2 = 0; q2 < 8; ++q2) a += red[q2*64 + tid];
      tscale[tid] = fmaxf(a, 0.f);      // h2
    }
    __syncthreads();
    if (tid < 10) {
      float a = bl3[tid];
      for (int k = 0; k < 64; ++k) a += tscale[k]*Wl3[k*10 + tid];
      dinv[tid] = fmaxf(a, 0.f);        // logits
    }
    __syncthreads();
    if (tid == 0) {
      float m = dinv[0];
      for (int i = 1; i < 10; ++i) m = fmaxf(m, dinv[i]);
      float s = 0.f;
      for (int i = 0; i < 10; ++i) s += expf(dinv[i] - m);
      red[0] = m; red[1] = logf(s);
    }
    __syncthreads();
    if (tid < 10) out[(size_t)g*10 + tid] = dinv[tid] - red[0] - red[1];
  }
}

extern "C" void kernel_launch(void* const* d_in, const int* in_sizes, int n_in,
                              void* d_out, int out_size, void* d_ws, size_t ws_size,
                              hipStream_t stream) {
  const float* x   = (const float*)d_in[0];
  const int*  srcI = (const int*)d_in[1];
  const int*  dstI = (const int*)d_in[2];
  const float* W1  = (const float*)d_in[3];
  const float* b1  = (const float*)d_in[4];
  const float* W2  = (const float*)d_in[5];
  const float* b2  = (const float*)d_in[6];
  const float* W3  = (const float*)d_in[7];
  const float* b3  = (const float*)d_in[8];
  const float* Ws1 = (const float*)d_in[9];
  const float* bs1 = (const float*)d_in[10];
  const float* Ws2 = (const float*)d_in[11];
  const float* bs2 = (const float*)d_in[12];
  const float* Ws3 = (const float*)d_in[13];
  const float* bs3 = (const float*)d_in[14];
  const float* Wl1 = (const float*)d_in[15];
  const float* bl1 = (const float*)d_in[16];
  const float* Wl2 = (const float*)d_in[17];
  const float* bl2 = (const float*)d_in[18];
  const float* Wl3 = (const float*)d_in[19];
  const float* bl3 = (const float*)d_in[20];
  float* out = (float*)d_out;

  short* WtAll = (short*)d_ws;   // 3 * 2 * 16384 shorts = 192 KB

  prep_wt<<<192, 256, 0, stream>>>(W1, W2, W3, WtAll);
  fused_net<<<NGRAPH, 1024, 0, stream>>>(x, srcI, dstI, WtAll,
                                         b1, Ws1, bs1, b2, Ws2, bs2, b3, Ws3, bs3,
                                         Wl1, bl1, Wl2, bl2, Wl3, bl3, out);
}

// Round 16
// 82.172 us; speedup vs baseline: 1.0459x; 1.0459x over previous
//
#include <hip/hip_runtime.h>
#include <math.h>

#define NGRAPH 256
#define NPG 256
#define HF 128
#define EPG 4096      // real edges per graph
#define EPG2 4352     // max CSR slots incl one self-edge per node
#define FSTR 132      // f32 row stride in tbufF (aliases hpair)
#define PSTR 136      // short row stride in hpair

typedef __attribute__((ext_vector_type(8))) short bf16x8;
typedef __attribute__((ext_vector_type(4))) float f32x4;

template<int N> struct IC { static constexpr int value = N; };
template<bool B> struct BC { static constexpr bool value = B; };

static __device__ __forceinline__ unsigned bcu(float f){ return __builtin_bit_cast(unsigned, f); }
static __device__ __forceinline__ float bcf(unsigned u){ return __builtin_bit_cast(float, u); }
static __device__ __forceinline__ unsigned rtn16(float f){
  unsigned u = bcu(f);
  return (u + 0x7FFFu + ((u >> 16) & 1u)) >> 16;
}

// ---------------- W transpose + split to bf16 hi/lo: Wt[n][k] ----------------
__global__ __launch_bounds__(256) void prep_wt(const float* __restrict__ W1,
                                               const float* __restrict__ W2,
                                               const float* __restrict__ W3,
                                               short* __restrict__ Wt) {
  int idx = blockIdx.x * 256 + threadIdx.x;
  int L = idx >> 14, r = idx & 16383;
  int k = r >> 7, n = r & 127;
  const float* W = (L == 0) ? W1 : (L == 1) ? W2 : W3;
  float w = W[k*128 + n];
  unsigned hi = rtn16(w);
  float lo = w - bcf(hi << 16);
  short* Whi = Wt + (size_t)L * 2 * 16384;
  short* Wlo = Whi + 16384;
  Whi[n*128 + k] = (short)hi;
  Wlo[n*128 + k] = (short)(bcu(lo) >> 16);
}

// sort compare-exchange step (descending key, ascending idx on ties)
#define BSTEP(OK, OI, KKc, Jc) do { \
  bool iLess = ((tid & (Jc)) == 0); \
  bool descR = ((tid & (KKc)) == 0); \
  bool myFirst = (kf > (OK)) || (kf == (OK) && ki < (OI)); \
  bool keep = (iLess == descR) ? myFirst : !myFirst; \
  if (!keep) { kf = (OK); ki = (OI); } \
} while (0)

// single-wave exclusive scan of cntA -> rloc + curA; rloc[NPG] = total
#define WAVE0_SCAN() do { \
  if (wid == 0) { \
    int b4 = lane*4; \
    int c0=cntA[b4+0], c1=cntA[b4+1], c2=cntA[b4+2], c3=cntA[b4+3]; \
    int tot = c0+c1+c2+c3; \
    int run = tot; \
    _Pragma("unroll") \
    for (int off=1; off<64; off<<=1) { \
      int u = __shfl_up(run, off); \
      run += (lane >= off) ? u : 0; \
    } \
    int st = run - tot; \
    rloc[b4+0]=(unsigned short)st; \
    rloc[b4+1]=(unsigned short)(st+c0); \
    rloc[b4+2]=(unsigned short)(st+c0+c1); \
    rloc[b4+3]=(unsigned short)(st+c0+c1+c2); \
    curA[b4+0]=st; curA[b4+1]=st+c0; curA[b4+2]=st+c0+c1; curA[b4+3]=st+c0+c1+c2; \
    if (lane == 63) rloc[NPG] = (unsigned short)run; \
  } \
} while (0)

// ---------------- whole network, one block per graph ----------------
__global__ __launch_bounds__(1024, 4)
void fused_net(
    const float* __restrict__ x,
    const int* __restrict__ srcI, const int* __restrict__ dstI,
    const short* __restrict__ WtAll,
    const float* __restrict__ b1, const float* __restrict__ Ws1, const float* __restrict__ bs1,
    const float* __restrict__ b2, const float* __restrict__ Ws2, const float* __restrict__ bs2,
    const float* __restrict__ b3, const float* __restrict__ Ws3, const float* __restrict__ bs3,
    const float* __restrict__ Wl1, const float* __restrict__ bl1,
    const float* __restrict__ Wl2, const float* __restrict__ bl2,
    const float* __restrict__ Wl3, const float* __restrict__ bl3,
    float* __restrict__ out)
{
  __shared__ __align__(16) short hpair[2][NPG*PSTR];   // 139264 B; aliased by tbufF
  __shared__ unsigned char colS[EPG2 + 8];             // compacted CSR (current ids), incl self
  __shared__ unsigned short rloc[NPG+2];
  __shared__ unsigned selM[8];                         // selection bitmask (current ids)
  __shared__ float dinv[NPG];
  __shared__ __align__(16) float bvec[HF];
  __shared__ __align__(16) float wsv[HF];
  __shared__ float score[NPG];
  __shared__ float tscale[NPG];                        // tq scratch / tanh scale
  __shared__ float skey[NPG];
  __shared__ int   sidx[NPG];
  __shared__ unsigned char rank8[NPG];                 // current id -> next id (0xFF dead)
  __shared__ unsigned char lut[NPG];                   // ORIGINAL id -> current id (0xFF dead)
  __shared__ __align__(16) float red[1024];            // readout max / MLP scratch
  __shared__ __align__(16) float red2[1024];           // readout sum
  __shared__ float zacc[2*HF];

  float* tbufF = (float*)&hpair[0][0];                 // [row][FSTR] f32, alias
  short* hp0 = &hpair[0][0];
  short* hp1 = &hpair[1][0];
  int* cntA = (int*)skey;                              // degree counts (alias: sort scratch)
  int* curA = sidx;

  int tid = threadIdx.x;
  int g = blockIdx.x;
  size_t nbase = (size_t)g * NPG;
  int lane = tid & 63, wid = tid >> 6;

  // ---- stage x into bf16 hi/lo pair ----
  const float4* X4 = (const float4*)(x + nbase*HF);
  #pragma unroll
  for (int i = 0; i < 8; ++i) {
    int f4 = tid + i*1024;
    int r = f4 >> 5, kq = f4 & 31;
    float4 val = X4[f4];
    unsigned rx = rtn16(val.x), ry = rtn16(val.y), rz = rtn16(val.z), rw = rtn16(val.w);
    uint2 ph; ph.x = rx | (ry << 16); ph.y = rz | (rw << 16);
    float lx = val.x - bcf(rx << 16), ly = val.y - bcf(ry << 16);
    float lz = val.z - bcf(rz << 16), lw = val.w - bcf(rw << 16);
    uint2 pl; pl.x = (bcu(lx) >> 16) | (bcu(ly) & 0xFFFF0000u);
    pl.y = (bcu(lz) >> 16) | (bcu(lw) & 0xFFFF0000u);
    *(uint2*)&hp0[r*PSTR + kq*4] = ph;
    *(uint2*)&hp1[r*PSTR + kq*4] = pl;
  }

  // ---- edges into registers (ORIGINAL local ids, kept all layers) ----
  int nb = g * NPG;
  int dloc[4], sloc[4];
  #pragma unroll
  for (int it = 0; it < 4; ++it) {
    int e = g*EPG + tid + it*1024;
    dloc[it] = dstI[e] - nb;
    sloc[it] = srcI[e] - nb;
  }

  // ---- initial CSR build (all alive, +1 self slot per node) + lut identity ----
  if (tid < NPG) { cntA[tid] = 1; lut[tid] = (unsigned char)tid; }
  __syncthreads();
  #pragma unroll
  for (int it = 0; it < 4; ++it) atomicAdd(&cntA[dloc[it]], 1);
  __syncthreads();
  WAVE0_SCAN();
  __syncthreads();
  #pragma unroll
  for (int it = 0; it < 4; ++it) {
    int slot = atomicAdd(&curA[dloc[it]], 1);
    colS[slot] = (unsigned char)sloc[it];
  }
  if (tid < NPG) colS[rloc[tid+1] - 1] = (unsigned char)tid;
  // NOTE: cntA (=skey) still holds degrees; layer 1 derives dinv from it.

  // ================= layer template =================
  auto run_layer = [&](auto nrc, auto kc, auto firstc, auto packc, auto buildc,
                       const short* Whi, const short* Wlo,
                       const float* bias, const float* Wsc, const float* bscp) {
    constexpr int NR = decltype(nrc)::value;      // rows in (compacted)
    constexpr int K  = decltype(kc)::value;       // rows out
    constexpr bool FIRST = decltype(firstc)::value;
    constexpr bool PACK  = decltype(packc)::value;
    constexpr bool BUILD = decltype(buildc)::value;  // build own CSR (counts from prev layer)
    constexpr int TPN = 1024 / NR;                // threads per node: 4,8,16
    constexpr int NI  = 32 / TPN;                 // float4s per thread: 8,4,2
    constexpr int SH  = (TPN == 4) ? 2 : ((TPN == 8) ? 3 : 4);
    constexpr int RT  = NR / 64;                  // transform row tiles per wave: 4,2,1
    int v = tid >> SH, q = tid & (TPN - 1);
    int cb0 = 4 * q;

    __syncthreads();   // B0: pack + counts (cntA) visible

    if (tid < HF) { bvec[tid] = bias[tid]; wsv[tid] = Wsc[tid]; }
    float bscv = bscp[0];
    if (tid < NR) dinv[tid] = 1.0f / sqrtf((float)cntA[tid]);
    if constexpr (BUILD) WAVE0_SCAN();   // wave0: counts -> rloc/curA (overlaps MFMA)

    // ---- transform: G = dinv * (h @ W), 4rg x 4cg waves, all active ----
    {
      int rg = wid & 3, cg = wid >> 2;
      int lr = lane & 15, lk8 = (lane >> 4) * 8;
      f32x4 tacc[RT][2] = {};
      #pragma unroll
      for (int kc2 = 0; kc2 < 4; ++kc2) {
        int k0 = kc2*32 + lk8;
        bf16x8 ah[RT], al[RT];
        #pragma unroll
        for (int rt = 0; rt < RT; ++rt) {
          int row = rg*(NR/4) + rt*16 + lr;
          ah[rt] = *(const bf16x8*)&hp0[row*PSTR + k0];
          al[rt] = *(const bf16x8*)&hp1[row*PSTR + k0];
        }
        #pragma unroll
        for (int ct = 0; ct < 2; ++ct) {
          int n = cg*32 + ct*16 + lr;
          bf16x8 bh = *(const bf16x8*)&Whi[n*HF + k0];
          bf16x8 bl = *(const bf16x8*)&Wlo[n*HF + k0];
          #pragma unroll
          for (int rt = 0; rt < RT; ++rt) {
            tacc[rt][ct] = __builtin_amdgcn_mfma_f32_16x16x32_bf16(ah[rt], bh, tacc[rt][ct], 0, 0, 0);
            tacc[rt][ct] = __builtin_amdgcn_mfma_f32_16x16x32_bf16(al[rt], bh, tacc[rt][ct], 0, 0, 0);
            tacc[rt][ct] = __builtin_amdgcn_mfma_f32_16x16x32_bf16(ah[rt], bl, tacc[rt][ct], 0, 0, 0);
          }
        }
      }
      __syncthreads();   // B1: pair reads done; dinv[]/rloc/curA visible
      #pragma unroll
      for (int rt = 0; rt < RT; ++rt) {
        int row0 = rg*(NR/4) + rt*16 + (lane >> 4)*4;
        float d0 = dinv[row0+0], d1 = dinv[row0+1], d2 = dinv[row0+2], d3 = dinv[row0+3];
        #pragma unroll
        for (int ct = 0; ct < 2; ++ct) {
          int c = cg*32 + ct*16 + (lane & 15);
          tbufF[(row0+0)*FSTR + c] = tacc[rt][ct][0] * d0;
          tbufF[(row0+1)*FSTR + c] = tacc[rt][ct][1] * d1;
          tbufF[(row0+2)*FSTR + c] = tacc[rt][ct][2] * d2;
          tbufF[(row0+3)*FSTR + c] = tacc[rt][ct][3] * d3;
        }
      }
    }
    if constexpr (BUILD) {
      // scatter kept edges into fresh CSR (overlaps epilogue; colS old is dead)
      #pragma unroll
      for (int it = 0; it < 4; ++it) {
        int d2 = lut[dloc[it]], s2 = lut[sloc[it]];
        if (d2 < NR && s2 < NR) {
          int slot = atomicAdd(&curA[d2], 1);
          colS[slot] = (unsigned char)s2;
        }
      }
      if (tid < NR) colS[rloc[tid+1] - 1] = (unsigned char)tid;  // self in last slot
    }
    __syncthreads();   // B2: G + CSR ready

    // ---- aggregation: TPN threads/node, 4-deep colS prefetch; tq via shfl ----
    float4 hv[NI];
    {
      float4 acc[NI];
      #pragma unroll
      for (int j = 0; j < NI; ++j) { acc[j].x = acc[j].y = acc[j].z = acc[j].w = 0.f; }
      int e0 = rloc[v], e1 = rloc[v+1];
      int sA = colS[e0], sB = colS[e0+1], sC = colS[e0+2], sD = colS[e0+3];
      int e = e0;
      for (; e + 1 < e1; e += 2) {
        int s0 = sA, s1 = sB;
        sA = sC; sB = sD; sC = colS[e+4]; sD = colS[e+5];
        const float* g0 = &tbufF[s0*FSTR + cb0];
        const float* g1 = &tbufF[s1*FSTR + cb0];
        #pragma unroll
        for (int j = 0; j < NI; ++j) {
          float4 t0 = *(const float4*)&g0[j*4*TPN];
          float4 t1 = *(const float4*)&g1[j*4*TPN];
          acc[j].x += t0.x + t1.x; acc[j].y += t0.y + t1.y;
          acc[j].z += t0.z + t1.z; acc[j].w += t0.w + t1.w;
        }
      }
      if (e < e1) {
        const float* g0 = &tbufF[sA*FSTR + cb0];
        #pragma unroll
        for (int j = 0; j < NI; ++j) {
          float4 t0 = *(const float4*)&g0[j*4*TPN];
          acc[j].x += t0.x; acc[j].y += t0.y; acc[j].z += t0.z; acc[j].w += t0.w;
        }
      }
      float dv = dinv[v];
      float p = 0.f;
      #pragma unroll
      for (int j = 0; j < NI; ++j) {
        int ci = cb0 + j*4*TPN;
        float4 bv = *(const float4*)&bvec[ci];
        float4 wv = *(const float4*)&wsv[ci];
        float4 a;
        a.x = fmaxf(fmaf(dv, acc[j].x, bv.x), 0.f);
        a.y = fmaxf(fmaf(dv, acc[j].y, bv.y), 0.f);
        a.z = fmaxf(fmaf(dv, acc[j].z, bv.z), 0.f);
        a.w = fmaxf(fmaf(dv, acc[j].w, bv.w), 0.f);
        hv[j] = a;
        p += a.x*wv.x + a.y*wv.y + a.z*wv.z + a.w*wv.w;
      }
      // butterfly across the TPN adjacent lanes of this node
      #pragma unroll
      for (int o = 1; o < TPN; o <<= 1) p += __shfl_xor(p, o);
      if (q == 0) tscale[v] = p * dv;       // tq = (h.Ws)*dinv
    }
    __syncthreads();   // B3: tq ready, G reads done

    // ---- score aggregation: prefetched CSR walk (incl self slot) ----
    if (tid < NR) {
      int e0 = rloc[tid], e1 = rloc[tid+1];
      float sa = 0.f;
      int sA = colS[e0], sB = colS[e0+1], sC = colS[e0+2], sD = colS[e0+3];
      for (int e = e0; e < e1; ++e) {
        int s = sA; sA = sB; sB = sC; sC = sD; sD = colS[e+4];
        sa += tscale[s];
      }
      score[tid] = dinv[tid] * sa + bscv;
    }
    __syncthreads();   // B5: scores ready

    // ---- top-K bitonic sort over NR; idle waves: selM clear + tanh ----
    float kf = -INFINITY; int ki = tid;
    if (tid < NR) {
      kf = score[tid];
      for (int kk = 2; kk <= 64; kk <<= 1)
        for (int j = kk >> 1; j > 0; j >>= 1) {
          float ok = __shfl_xor(kf, j);
          int   oi = __shfl_xor(ki, j);
          BSTEP(ok, oi, kk, j);
        }
    } else {
      if (tid < NR + 8) selM[tid - NR] = 0u;
      int vt = tid - NR;
      if (vt < NR) tscale[vt] = tanhf(score[vt]);   // unconditional tanh (writes rank-gated)
    }

    if constexpr (NR == 256) {
      if (tid < NR) { skey[tid] = kf; sidx[tid] = ki; }
      __syncthreads();
      if (tid < NR) {
        int l = tid ^ 64; float ok = skey[l]; int oi = sidx[l];
        BSTEP(ok, oi, 128, 64);
        for (int j = 32; j > 0; j >>= 1) {
          float sk = __shfl_xor(kf, j); int si = __shfl_xor(ki, j);
          BSTEP(sk, si, 128, j);
        }
      }
      __syncthreads();
      if (tid < NR) { skey[tid] = kf; sidx[tid] = ki; }
      __syncthreads();
      if (tid < NR) {
        int l = tid ^ 128; float ok = skey[l]; int oi = sidx[l];
        BSTEP(ok, oi, 256, 128);
      }
      __syncthreads();
      if (tid < NR) { skey[tid] = kf; sidx[tid] = ki; }
      __syncthreads();
      if (tid < NR) {
        int l = tid ^ 64; float ok = skey[l]; int oi = sidx[l];
        BSTEP(ok, oi, 256, 64);
        for (int j = 32; j > 0; j >>= 1) {
          float sk = __shfl_xor(kf, j); int si = __shfl_xor(ki, j);
          BSTEP(sk, si, 256, j);
        }
      }
    } else if constexpr (NR == 128) {
      if (tid < NR) { skey[tid] = kf; sidx[tid] = ki; }
      __syncthreads();
      if (tid < NR) {
        int l = tid ^ 64; float ok = skey[l]; int oi = sidx[l];
        BSTEP(ok, oi, 128, 64);
        for (int j = 32; j > 0; j >>= 1) {
          float sk = __shfl_xor(kf, j); int si = __shfl_xor(ki, j);
          BSTEP(sk, si, 128, j);
        }
      }
    }
    if constexpr (NR == 64) __syncthreads();       // separate clear from publish
    if constexpr (NR != 64 && NR != 256) __syncthreads();
    if (tid < K) atomicOr(&selM[ki >> 5], 1u << (ki & 31));
    __syncthreads();   // B6: selection published (skey/cntA now free)

    // ---- rank (order-preserving compaction) + next-layer count init ----
    if (tid < NR) {
      unsigned wsel = selM[tid >> 5];
      bool sel = (wsel >> (tid & 31)) & 1;
      int r = __popc(wsel & ((1u << (tid & 31)) - 1u));
      for (int w = 0; w < (tid >> 5); ++w) r += __popc(selM[w]);
      rank8[tid] = sel ? (unsigned char)r : (unsigned char)0xFF;
    }
    if constexpr (PACK) {
      if (tid < NPG) cntA[tid] = (tid < K) ? 1 : 0;   // self-loop seed for next layer
    }
    __syncthreads();   // B7: rank8 ready
    if (tid < NPG) {
      int lv = lut[tid];
      lut[tid] = (lv < NR) ? rank8[lv] : (unsigned char)0xFF;
    }

    // ---- scale + write f32 h' at NEW (compacted) rows ----
    int rk = rank8[v];
    {
      float ts = tscale[v];
      if (rk != 0xFF) {
        #pragma unroll
        for (int j = 0; j < NI; ++j) {
          hv[j].x *= ts; hv[j].y *= ts; hv[j].z *= ts; hv[j].w *= ts;
          *(float4*)&tbufF[rk*FSTR + cb0 + j*4*TPN] = hv[j];
        }
      }
    }
    __syncthreads();   // B8: h' f32 ready; lut final

    // ---- readout partials + next-layer degree counts ----
    {
      constexpr int RPG = K / 8;
      int f = tid & 127, vg = tid >> 7;
      float mx = -INFINITY, sm = 0.f;
      #pragma unroll
      for (int vr = 0; vr < RPG; ++vr) {
        float val = tbufF[(vg*RPG + vr)*FSTR + f];
        mx = fmaxf(mx, val); sm += val;
      }
      red[vg*HF + f] = mx;
      red2[vg*HF + f] = sm;
    }
    if constexpr (PACK) {
      #pragma unroll
      for (int it = 0; it < 4; ++it) {
        int d2 = lut[dloc[it]], s2 = lut[sloc[it]];
        if (d2 < K && s2 < K) atomicAdd(&cntA[d2], 1);
      }
    }
    __syncthreads();   // B9: tbufF reads done; red/red2 ready; counts done
    if (tid < HF) {
      float zm = red[tid];
      float zs = red2[tid];
      #pragma unroll
      for (int q2 = 1; q2 < 8; ++q2) {
        zm = fmaxf(zm, red[q2*HF + tid]);
        zs += red2[q2*HF + tid];
      }
      float mn = zs / (float)K;
      if (FIRST) { zacc[tid] = zm; zacc[HF + tid] = mn; }
      else       { zacc[tid] += zm; zacc[HF + tid] += mn; }
    }

    if constexpr (PACK) {
      // ---- pack scaled h' into bf16 pair at NEW rows (tbufF reads done) ----
      if (rk != 0xFF) {
        #pragma unroll
        for (int j = 0; j < NI; ++j) {
          int ci = cb0 + j*4*TPN;
          float4 val = hv[j];
          unsigned rx = rtn16(val.x), ry = rtn16(val.y), rz = rtn16(val.z), rw = rtn16(val.w);
          uint2 ph; ph.x = rx | (ry << 16); ph.y = rz | (rw << 16);
          float lx = val.x - bcf(rx << 16), ly = val.y - bcf(ry << 16);
          float lz = val.z - bcf(rz << 16), lw = val.w - bcf(rw << 16);
          uint2 pl; pl.x = (bcu(lx) >> 16) | (bcu(ly) & 0xFFFF0000u);
          pl.y = (bcu(lz) >> 16) | (bcu(lw) & 0xFFFF0000u);
          *(uint2*)&hp0[rk*PSTR + ci] = ph;
          *(uint2*)&hp1[rk*PSTR + ci] = pl;
        }
      }
    }
  };

  run_layer(IC<256>{}, IC<128>{}, BC<true>{},  BC<true>{},  BC<false>{},
            WtAll,         WtAll + 16384, b1, Ws1, bs1);
  run_layer(IC<128>{}, IC<64>{},  BC<false>{}, BC<true>{},  BC<true>{},
            WtAll + 32768, WtAll + 49152, b2, Ws2, bs2);
  run_layer(IC<64>{},  IC<32>{},  BC<false>{}, BC<false>{}, BC<true>{},
            WtAll + 65536, WtAll + 81920, b3, Ws3, bs3);

  __syncthreads();

  // ---- MLP head + log_softmax ----
  {
    int o = tid & 127, kg = tid >> 7;
    float p = 0.f;
    int k0 = kg*32;
    for (int k = k0; k < k0+32; ++k) p += zacc[k]*Wl1[k*HF + o];
    red[kg*HF + o] = p;
    __syncthreads();
    if (tid < HF) {
      float a = bl1[tid];
      #pragma unroll
      for (int q2 = 0; q2 < 8; ++q2) a += red[q2*HF + tid];
      score[tid] = fmaxf(a, 0.f);       // h1
    }
    __syncthreads();
    if (tid < 512) {
      int o2 = tid & 63, kg2 = tid >> 6;
      float p2 = 0.f;
      int k0b = kg2*16;
      for (int k = k0b; k < k0b+16; ++k) p2 += score[k]*Wl2[k*64 + o2];
      red[kg2*64 + o2] = p2;
    }
    __syncthreads();
    if (tid < 64) {
      float a = bl2[tid];
      #pragma unroll
      for (int q2 = 0; q2 < 8; ++q2) a += red[q2*64 + tid];
      tscale[tid] = fmaxf(a, 0.f);      // h2
    }
    __syncthreads();
    if (tid < 10) {
      float a = bl3[tid];
      for (int k = 0; k < 64; ++k) a += tscale[k]*Wl3[k*10 + tid];
      dinv[tid] = fmaxf(a, 0.f);        // logits
    }
    __syncthreads();
    if (tid == 0) {
      float m = dinv[0];
      for (int i = 1; i < 10; ++i) m = fmaxf(m, dinv[i]);
      float s = 0.f;
      for (int i = 0; i < 10; ++i) s += expf(dinv[i] - m);
      red[0] = m; red[1] = logf(s);
    }
    __syncthreads();
    if (tid < 10) out[(size_t)g*10 + tid] = dinv[tid] - red[0] - red[1];
  }
}

extern "C" void kernel_launch(void* const* d_in, const int* in_sizes, int n_in,
                              void* d_out, int out_size, void* d_ws, size_t ws_size,
                              hipStream_t stream) {
  const float* x   = (const float*)d_in[0];
  const int*  srcI = (const int*)d_in[1];
  const int*  dstI = (const int*)d_in[2];
  const float* W1  = (const float*)d_in[3];
  const float* b1  = (const float*)d_in[4];
  const float* W2  = (const float*)d_in[5];
  const float* b2  = (const float*)d_in[6];
  const float* W3  = (const float*)d_in[7];
  const float* b3  = (const float*)d_in[8];
  const float* Ws1 = (const float*)d_in[9];
  const float* bs1 = (const float*)d_in[10];
  const float* Ws2 = (const float*)d_in[11];
  const float* bs2 = (const float*)d_in[12];
  const float* Ws3 = (const float*)d_in[13];
  const float* bs3 = (const float*)d_in[14];
  const float* Wl1 = (const float*)d_in[15];
  const float* bl1 = (const float*)d_in[16];
  const float* Wl2 = (const float*)d_in[17];
  const float* bl2 = (const float*)d_in[18];
  const float* Wl3 = (const float*)d_in[19];
  const float* bl3 = (const float*)d_in[20];
  float* out = (float*)d_out;

  short* WtAll = (short*)d_ws;   // 3 * 2 * 16384 shorts = 192 KB

  prep_wt<<<192, 256, 0, stream>>>(W1, W2, W3, WtAll);
  fused_net<<<NGRAPH, 1024, 0, stream>>>(x, srcI, dstI, WtAll,
                                         b1, Ws1, bs1, b2, Ws2, bs2, b3, Ws3, bs3,
                                         Wl1, bl1, Wl2, bl2, Wl3, bl3, out);
}